// Round 14
// baseline (7020.260 us; speedup 1.0000x reference)
//
#include <hip/hip_runtime.h>

#define NB 4
#define NPT 32768
#define QPT 8192          // points per quarter-cloud
#define CIN 128
#define COUT 256
#define NS 2048
#define THR 512
#define PPT 16            // points per thread (QPT / THR)

// ws float-offset layout
#define WS_G 0            // 128*128 Gram
#define WS_FSUM 16384     // 128 column sums
#define WS_SLOT 16512     // 4 clouds x 2 par x 32 wave-slots u64 = 1024 floats
#define WS_GSCALE 17536   // 256
#define WS_GBIAS 17792    // 256
#define WS_IDX 18048      // 8192 ints

// d_out float-offset layout
#define OUT_COORD 0
#define OUT_FEAT 24576
#define OUT_OFFS 2121728

// Established rounds 1-13:
//  * 4 blocks/cloud is FORCED (coords must be LDS-resident: 384 KB/cloud vs
//    160 KB/CU) -> cross-block exchange unavoidable.
//  * agent-scope atomics are memory-side (~800 cyc/way); r13 falsified the
//    same-XCD L2 fast path (%8 co-location doesn't hold / sc0 can't see
//    agent stores): landed exactly in the pre-committed failure band.
//  * Poll thinning works (r12, +7%); poll flooding kills (r10).
//  * r12's residual exchange chain: butterfly -> LDS atomicMax -> barrier
//    -> winner recheck -> store. THIS ROUND removes the boxed serialization:
//    per-wave IMMEDIATE key stores (32 slots/cloud/par); only wave0 polls
//    (one 256B request/round + s_sleep); wave0 publishes the merged winner
//    to a tagged LDS mailbox; other waves spin on LDS. ZERO barriers in the
//    loop. Winner = max of 32 wave keys; tags gate on all 32 contributed.
//  * Slot/mailbox reuse at parity distance 2 safe: every wave posts key(it+1)
//    only after consuming res(it) (program order); wave0s also post keys, so
//    any block's poll(it+1) completing proves every wave finished poll/spin
//    of (it) -> store(it+2) cannot clobber an unread (it) value.
//  * Tagged monotone key it<<48 | dbits<<15 | (32767-gidx): bigger dist
//    wins, tie -> lower index (np.argmax first-occurrence); stale/losing
//    values lose the max automatically. memset clears slots per launch.
//  * WRITE ~66 MB = Gram's memory-side atomics (expected). rocprof inflates
//    spin kernels -> compare unprofiled totals only.
__global__ __launch_bounds__(THR) void fused1(
    const float* __restrict__ coord, const float* __restrict__ feat,
    float* __restrict__ wsf, int* __restrict__ wsi,
    unsigned long long* __restrict__ slots)
{
  __shared__ float2 lxy[QPT];                 // 65536 B
  __shared__ float lz[QPT];                   // 32768 B
  __shared__ unsigned long long s_res[2];     // tagged result mailbox
  __shared__ float s_fs[4][128];              // colsum scratch (2 KB)

  const int bid = blockIdx.x;
  const int t = threadIdx.x;
  const bool is_fps = (bid < 32) && ((bid & 7) < 4);

  if (is_fps) {
    // ---------------- FPS: cloud cl, quarter h ----------------
    const int cl = bid & 3;
    const int h = bid >> 3;                   // 0..3
    const int gbase = h * QPT;
    const float* xyz = coord + (size_t)cl * NPT * 3;
    int* idx_out = wsi + cl * NS;
    unsigned long long* slotc = slots + (size_t)cl * 128;  // [par][32] u64

    float dv[PPT];
#pragma unroll
    for (int j = 0; j < PPT; ++j) {
      const int l = j * THR + t;
      const int p = gbase + l;
      lxy[l] = make_float2(xyz[p * 3 + 0], xyz[p * 3 + 1]);
      lz[l] = xyz[p * 3 + 2];
      dv[j] = 1e10f;
    }
    if (t == 0) {
      if (h == 0) idx_out[0] = 0;             // every cloud writes sample 0
      s_res[0] = s_res[1] = 0ull;             // tag 0 < any it>=1
    }
    float cx = xyz[0], cy = xyz[1], cz = xyz[2];   // same-address broadcast
    __syncthreads();                          // LDS coords + mailbox ready

    const int lane = t & 63;
    const int wid = t >> 6;                   // wave 0..7
    const int wslot = h * 8 + wid;            // global wave slot 0..31

    for (int it = 1; it < NS; ++it) {
      const int par = it & 1;
      const unsigned long long utag = (unsigned long long)it;
      unsigned long long* slotp = slotc + par * 32;
      float bd = -1.f;
      int bj = 0;
      // exact numpy-f32 distance: plain muls (asm blocks fma contraction),
      // (sx+sy)+sz, v_min_f32 update; argmax tracked inline (strict > keeps
      // lowest j = lowest global index within this thread's stride).
#pragma unroll
      for (int j = 0; j < PPT; ++j) {
        const int l = j * THR + t;
        const float2 xy = lxy[l];
        const float zz = lz[l];
        float dx = xy.x - cx, dy = xy.y - cy, dz = zz - cz;
        float sx = dx * dx, sy = dy * dy, sz = dz * dz;
        asm volatile("" : "+v"(sx), "+v"(sy), "+v"(sz));
        float nd = fminf(dv[j], (sx + sy) + sz);
        dv[j] = nd;
        if (nd > bd) { bd = nd; bj = j; }
      }
      const int gidx = gbase + bj * THR + t;
      // tagged monotone key: bigger dist wins, tie -> lower idx (np.argmax)
      unsigned long long wkey =
          (utag << 48) |
          ((unsigned long long)(unsigned)__float_as_int(bd) << 15) |
          (unsigned)(32767 - gidx);
#pragma unroll
      for (int o = 32; o > 0; o >>= 1) {
        unsigned long long ok = __shfl_xor(wkey, o, 64);
        wkey = ok > wkey ? ok : wkey;
      }
      if (lane == 0)                          // IMMEDIATE per-wave store
        __hip_atomic_store(&slotp[wslot], wkey,
                           __ATOMIC_RELAXED, __HIP_MEMORY_SCOPE_AGENT);
      unsigned long long res;
      if (wid == 0) {
        // wave0: poll all 32 wave-slots (one 256B request per round)
        unsigned long long v;
        for (;;) {
          v = __hip_atomic_load(&slotp[lane & 31],
                                __ATOMIC_RELAXED, __HIP_MEMORY_SCOPE_AGENT);
          if (__all((int)((v >> 48) == utag))) break;
          __builtin_amdgcn_s_sleep(1);
        }
#pragma unroll
        for (int o = 16; o > 0; o >>= 1) {    // max over the 32 slot values
          unsigned long long ov = __shfl_xor(v, o, 64);
          v = ov > v ? ov : v;
        }
        if (lane == 0) {
          __hip_atomic_store(&s_res[par], v,
                             __ATOMIC_RELAXED, __HIP_MEMORY_SCOPE_WORKGROUP);
          if (h == 0) idx_out[it] = 32767 - (int)(v & 0x7fff);
        }
        res = __shfl(v, 0, 64);
      } else {
        // other waves: spin on the tagged LDS mailbox (broadcast reads)
        do {
          res = __hip_atomic_load(&s_res[par],
                                  __ATOMIC_RELAXED, __HIP_MEMORY_SCOPE_WORKGROUP);
        } while ((res >> 48) != utag);
      }
      const int widx = 32767 - (int)(res & 0x7fff);
      cx = xyz[widx * 3 + 0];                 // same-address broadcast (L2)
      cy = xyz[widx * 3 + 1];
      cz = xyz[widx * 3 + 2];
    }
  } else {
    // non-FPS linear index: 16 fillers inside bid<32, rest from 32 up
    const int g = (bid < 32) ? ((bid >> 3) * 4 + (bid & 7) - 4) : (bid - 16);
    if (g < 128) {
      // ---------------- Gram partial: G += chunk^T chunk ----------------
      const float* fr = feat + (size_t)g * 1024 * CIN;
      const int ti = (t & 31) * 4;
      const int tj = (t >> 5) * 8;
      float acc[4][8];
#pragma unroll
      for (int a = 0; a < 4; ++a)
#pragma unroll
        for (int b2 = 0; b2 < 8; ++b2) acc[a][b2] = 0.f;
#pragma unroll 4
      for (int r = 0; r < 1024; ++r) {
        const float* rowp = fr + r * CIN;
        float4 a4 = *(const float4*)(rowp + ti);
        float4 b4 = *(const float4*)(rowp + tj);
        float4 b5 = *(const float4*)(rowp + tj + 4);
        float av[4] = {a4.x, a4.y, a4.z, a4.w};
        float bv[8] = {b4.x, b4.y, b4.z, b4.w, b5.x, b5.y, b5.z, b5.w};
#pragma unroll
        for (int a = 0; a < 4; ++a)
#pragma unroll
          for (int b2 = 0; b2 < 8; ++b2) acc[a][b2] += av[a] * bv[b2];
      }
      float* G = wsf + WS_G;
#pragma unroll
      for (int a = 0; a < 4; ++a)
#pragma unroll
        for (int b2 = 0; b2 < 8; ++b2)
          atomicAdd(&G[(ti + a) * CIN + (tj + b2)], acc[a][b2]);
    } else {
      // ---------------- column sums of feat ----------------
      const int fb = g - 128;             // 0..7
      const size_t base = (size_t)fb * 16384;
      const int c = t & 127, rg = t >> 7; // 0..3
      float s = 0.f;
      for (int r = rg; r < 16384; r += 4)
        s += feat[(base + r) * CIN + c];
      s_fs[rg][c] = s;
      __syncthreads();
      if (t < 128) {
        float v = s_fs[0][t] + s_fs[1][t] + s_fs[2][t] + s_fs[3][t];
        atomicAdd(&wsf[WS_FSUM + t], v);
      }
    }
  }
}

// mean[c] = (fsum . W[c]) / M ; E[x^2][c] = W[c]^T G W[c] / M
__global__ __launch_bounds__(128) void finalize_k(
    const float* __restrict__ W, const float* __restrict__ gamma,
    const float* __restrict__ beta, float* __restrict__ wsf)
{
  const int c = blockIdx.x, i = threadIdx.x;
  const float* G = wsf + WS_G;
  const float* fsum = wsf + WS_FSUM;
  const float* Gi = G + i * CIN;
  const float* Wc = W + c * CIN;
  float td = 0.f;
#pragma unroll 8
  for (int j = 0; j < CIN; j += 4) {
    float4 g4 = *(const float4*)(Gi + j);
    float4 w4 = *(const float4*)(Wc + j);
    td += g4.x * w4.x + g4.y * w4.y + g4.z * w4.z + g4.w * w4.w;
  }
  const float wci = Wc[i];
  float q = wci * td;
  float m = fsum[i] * wci;
#pragma unroll
  for (int o = 32; o > 0; o >>= 1) {
    q += __shfl_xor(q, o, 64);
    m += __shfl_xor(m, o, 64);
  }
  __shared__ float sq[2], sm[2];
  if ((i & 63) == 0) { sq[i >> 6] = q; sm[i >> 6] = m; }
  __syncthreads();
  if (i == 0) {
    const float inv_m = 1.f / 131072.f;
    float mean = (sm[0] + sm[1]) * inv_m;
    float e2 = (sq[0] + sq[1]) * inv_m;
    float var = e2 - mean * mean;
    float rstd = rsqrtf(var + 1e-5f);
    float gs = gamma[c] * rstd;
    wsf[WS_GSCALE + c] = gs;
    wsf[WS_GBIAS + c] = beta[c] - mean * gs;
  }
}

// recompute x rows only at sampled indices, normalize + relu, gather coords
__global__ __launch_bounds__(256) void gather_k(
    const float* __restrict__ coord, const float* __restrict__ feat,
    const float* __restrict__ W, const float* __restrict__ wsf,
    const int* __restrict__ wsi, float* __restrict__ out)
{
  const int p = blockIdx.x, t = threadIdx.x;
  const int b = p >> 11;
  const int idx = wsi[p];
  const size_t row = (size_t)b * NPT + idx;
  __shared__ float lf[CIN];
  if (t < CIN) lf[t] = feat[row * CIN + t];
  __syncthreads();
  const float* Wc = W + t * CIN;
  float acc = 0.f;
#pragma unroll 8
  for (int k = 0; k < CIN; k += 4) {
    float4 w4 = *(const float4*)(Wc + k);
    acc += lf[k] * w4.x + lf[k + 1] * w4.y + lf[k + 2] * w4.z + lf[k + 3] * w4.w;
  }
  float y = fmaxf(fmaf(acc, wsf[WS_GSCALE + t], wsf[WS_GBIAS + t]), 0.f);
  out[OUT_FEAT + (size_t)p * COUT + t] = y;
  if (t < 3) out[OUT_COORD + p * 3 + t] = coord[row * 3 + t];
  if (p == 0 && t < 4) out[OUT_OFFS + t] = (float)((t + 1) * NS);
}

extern "C" void kernel_launch(void* const* d_in, const int* in_sizes, int n_in,
                              void* d_out, int out_size, void* d_ws, size_t ws_size,
                              hipStream_t stream)
{
  const float* coord = (const float*)d_in[0];
  const float* feat  = (const float*)d_in[1];
  // d_in[2] = offset (implied by constants)
  const float* W     = (const float*)d_in[3];
  const float* gamma = (const float*)d_in[4];
  const float* beta  = (const float*)d_in[5];
  float* wsf = (float*)d_ws;
  int* wsi = (int*)(wsf + WS_IDX);
  unsigned long long* slots = (unsigned long long*)(wsf + WS_SLOT);
  float* out = (float*)d_out;

  // zero Gram + colsum accumulators AND all wave-slots (kills stale tags
  // across graph replays; stream-ordered before fused1)
  hipMemsetAsync(d_ws, 0, (WS_SLOT + 1024) * sizeof(float), stream);

  fused1<<<152, THR, 0, stream>>>(coord, feat, wsf, wsi, slots);
  finalize_k<<<COUT, 128, 0, stream>>>(W, gamma, beta, wsf);
  gather_k<<<NB * NS, 256, 0, stream>>>(coord, feat, W, wsf, wsi, out);
}

// Round 15
// 5567.543 us; speedup vs baseline: 1.2609x; 1.2609x over previous
//
#include <hip/hip_runtime.h>

#define NB 4
#define NPT 32768
#define QPT 8192          // points per quarter-cloud
#define CIN 128
#define COUT 256
#define NS 2048
#define THR 512
#define PPT 16            // points per thread (QPT / THR)

// ws float-offset layout
#define WS_G 0            // 128*128 Gram
#define WS_FSUM 16384     // 128 column sums
#define WS_SLOT 16512     // 4 clouds x 2 par x 4 blk x 4 u64 = 256 floats
#define WS_GSCALE 16768   // 256
#define WS_GBIAS 17024    // 256
#define WS_IDX 17280      // 8192 ints

// d_out float-offset layout
#define OUT_COORD 0
#define OUT_FEAT 24576
#define OUT_OFFS 2121728

// Established rounds 1-14 (exchange-structure ranking is now complete):
//  r12 (4 slots + LDS max + barrier + thinned poll) 4416 < r8 4746 <
//  r13 5025 < r9 5091 < r14 7020 < r10 7646  -> fewer sync participants
//  and less memory-side traffic win; barrier-free 32-slot designs lose
//  (slowest-of-32 gating + store flood). agent atomics are memory-side
//  (~800 cyc/way); %8 XCD co-location is falsified (r13). Compute is not
//  the bottleneck; coords must be LDS-resident (384 KB/cloud >> 160 KB/CU)
//  so 4 blocks/cloud + cross-block exchange is forced.
// THIS ROUND = r12 structure + two serial-path cuts:
//  (1) centroid rides the exchange: winner stores THREE self-tagged words
//      w0=tag|dbits|invidx, w1=tag|cx|cyhi, w2=tag|cylo|cz (per-word tags
//      make store visibility order irrelevant; bit-exact repack). Kills the
//      post-poll centroid L2 fetch (~250 cyc).
//  (2) only wave0 polls globally (lanes 0-15, one 128B request/round);
//      waves 1-7 spin on a tagged LDS mailbox (broadcast reads). 8x less
//      memory-side poll traffic than r12.
//  Reuse at parity distance 2 stays safe: my store(it+2) is post-barrier
//  (it+2) <- my waves consumed mailbox(it+1) <- my wave0 passed poll(it+1)
//  <- all blocks stored (it+1), post their barrier(it+1) <- their waves
//  consumed (it) -> no unread (it) value is ever clobbered.
//  Keys tagged monotone -> no LDS/slot resets needed; memset clears slots
//  each launch (graph replays deterministic). WRITE ~66 MB = Gram atomics.
//  rocprof inflates spin kernels -> compare unprofiled totals only.
__global__ __launch_bounds__(THR) void fused1(
    const float* __restrict__ coord, const float* __restrict__ feat,
    float* __restrict__ wsf, int* __restrict__ wsi,
    unsigned long long* __restrict__ slots)
{
  __shared__ float2 lxy[QPT];                 // 65536 B
  __shared__ float lz[QPT];                   // 32768 B
  __shared__ unsigned long long s_key[2];     // block argmax (tagged, no reset)
  __shared__ unsigned long long s_res[2][2];  // mailbox: centroid words w1,w2
  __shared__ float s_fs[4][128];              // colsum scratch (2 KB)

  const int bid = blockIdx.x;
  const int t = threadIdx.x;
  const bool is_fps = (bid < 32) && ((bid & 7) < 4);

  if (is_fps) {
    // ---------------- FPS: cloud cl, quarter h ----------------
    const int cl = bid & 3;
    const int h = bid >> 3;                   // 0..3
    const int gbase = h * QPT;
    const float* xyz = coord + (size_t)cl * NPT * 3;
    int* idx_out = wsi + cl * NS;
    unsigned long long* slotc = slots + (size_t)cl * 32;  // [par][blk][4]

    float dv[PPT];
#pragma unroll
    for (int j = 0; j < PPT; ++j) {
      const int l = j * THR + t;
      const int p = gbase + l;
      lxy[l] = make_float2(xyz[p * 3 + 0], xyz[p * 3 + 1]);
      lz[l] = xyz[p * 3 + 2];
      dv[j] = 1e10f;
    }
    if (t == 0) {
      if (h == 0) idx_out[0] = 0;             // every cloud writes sample 0
      s_key[0] = s_key[1] = 0ull;             // tag 0 < any it>=1
      s_res[0][0] = s_res[0][1] = 0ull;
      s_res[1][0] = s_res[1][1] = 0ull;
    }
    float cx = xyz[0], cy = xyz[1], cz = xyz[2];   // same-address broadcast
    __syncthreads();                          // LDS coords + mailboxes ready

    const int lane = t & 63;
    const int wid = t >> 6;                   // wave 0..7

    for (int it = 1; it < NS; ++it) {
      const int par = it & 1;
      const unsigned long long utag = (unsigned long long)it;
      float bd = -1.f;
      int bj = 0;
      // exact numpy-f32 distance: plain muls (asm blocks fma contraction),
      // (sx+sy)+sz, v_min_f32 update; argmax tracked inline (strict > keeps
      // lowest j = lowest global index within this thread's stride).
#pragma unroll
      for (int j = 0; j < PPT; ++j) {
        const int l = j * THR + t;
        const float2 xy = lxy[l];
        const float zz = lz[l];
        float dx = xy.x - cx, dy = xy.y - cy, dz = zz - cz;
        float sx = dx * dx, sy = dy * dy, sz = dz * dz;
        asm volatile("" : "+v"(sx), "+v"(sy), "+v"(sz));
        float nd = fminf(dv[j], (sx + sy) + sz);
        dv[j] = nd;
        if (nd > bd) { bd = nd; bj = j; }
      }
      const int gidx = gbase + bj * THR + t;
      // tagged monotone key: bigger dist wins, tie -> lower idx (np.argmax)
      const unsigned long long tkey =
          (utag << 48) |
          ((unsigned long long)(unsigned)__float_as_int(bd) << 15) |
          (unsigned)(32767 - gidx);
      unsigned long long wkey = tkey;
#pragma unroll
      for (int o = 32; o > 0; o >>= 1) {
        unsigned long long ok = __shfl_xor(wkey, o, 64);
        wkey = ok > wkey ? ok : wkey;
      }
      if (lane == 0) atomicMax(&s_key[par], wkey);
      __syncthreads();                        // the ONLY barrier per iter
      const unsigned long long skey = s_key[par];
      if (tkey == skey) {                     // unique winner thread
        const int l = bj * THR + t;           // winner's point = new centroid
        const unsigned cxb = __float_as_uint(lxy[l].x);
        const unsigned cyb = __float_as_uint(lxy[l].y);
        const unsigned czb = __float_as_uint(lz[l]);
        const unsigned long long w1 =
            (utag << 48) | ((unsigned long long)cxb << 16) | (cyb >> 16);
        const unsigned long long w2 =
            (utag << 48) | ((unsigned long long)(cyb & 0xFFFFu) << 32) | czb;
        unsigned long long* myslot = &slotc[par * 16 + h * 4];
        __hip_atomic_store(&myslot[0], skey,
                           __ATOMIC_RELAXED, __HIP_MEMORY_SCOPE_AGENT);
        __hip_atomic_store(&myslot[1], w1,
                           __ATOMIC_RELAXED, __HIP_MEMORY_SCOPE_AGENT);
        __hip_atomic_store(&myslot[2], w2,
                           __ATOMIC_RELAXED, __HIP_MEMORY_SCOPE_AGENT);
      }
      unsigned long long res1, res2;
      if (wid == 0) {
        // wave0: poll the 16-word cloud region (one 128B request/round);
        // word 3 of each block is padding -> skipped in the predicate
        unsigned long long v = 0;
        unsigned long long* base = &slotc[par * 16];
        for (;;) {
          if (lane < 16)
            v = __hip_atomic_load(&base[lane],
                                  __ATOMIC_RELAXED, __HIP_MEMORY_SCOPE_AGENT);
          const bool ok = (lane >= 16) || ((lane & 3) == 3) ||
                          ((v >> 48) == utag);
          if (__all((int)ok)) break;
          __builtin_amdgcn_s_sleep(1);
        }
        const unsigned long long k0 = __shfl(v, 0, 64);
        const unsigned long long k1 = __shfl(v, 4, 64);
        const unsigned long long k2 = __shfl(v, 8, 64);
        const unsigned long long k3 = __shfl(v, 12, 64);
        unsigned long long kb = k0; int wb = 0;
        if (k1 > kb) { kb = k1; wb = 1; }
        if (k2 > kb) { kb = k2; wb = 2; }
        if (k3 > kb) { kb = k3; wb = 3; }     // keys unique (idx unique)
        res1 = __shfl(v, wb * 4 + 1, 64);
        res2 = __shfl(v, wb * 4 + 2, 64);
        if (lane == 0) {
          __hip_atomic_store(&s_res[par][0], res1,
                             __ATOMIC_RELAXED, __HIP_MEMORY_SCOPE_WORKGROUP);
          __hip_atomic_store(&s_res[par][1], res2,
                             __ATOMIC_RELAXED, __HIP_MEMORY_SCOPE_WORKGROUP);
          if (h == 0) idx_out[it] = 32767 - (int)(kb & 0x7fff);
        }
      } else {
        // waves 1-7: spin on the tagged LDS mailbox (broadcast reads)
        do {
          res1 = __hip_atomic_load(&s_res[par][0],
                                   __ATOMIC_RELAXED, __HIP_MEMORY_SCOPE_WORKGROUP);
          res2 = __hip_atomic_load(&s_res[par][1],
                                   __ATOMIC_RELAXED, __HIP_MEMORY_SCOPE_WORKGROUP);
        } while (((res1 >> 48) != utag) || ((res2 >> 48) != utag));
      }
      // unpack centroid (bit-exact round trip)
      const unsigned cxb = (unsigned)((res1 >> 16) & 0xFFFFFFFFull);
      const unsigned cyb = (unsigned)(((res1 & 0xFFFFull) << 16) |
                                      ((res2 >> 32) & 0xFFFFull));
      const unsigned czb = (unsigned)(res2 & 0xFFFFFFFFull);
      cx = __uint_as_float(cxb);
      cy = __uint_as_float(cyb);
      cz = __uint_as_float(czb);
    }
  } else {
    // non-FPS linear index: 16 fillers inside bid<32, rest from 32 up
    const int g = (bid < 32) ? ((bid >> 3) * 4 + (bid & 7) - 4) : (bid - 16);
    if (g < 128) {
      // ---------------- Gram partial: G += chunk^T chunk ----------------
      const float* fr = feat + (size_t)g * 1024 * CIN;
      const int ti = (t & 31) * 4;
      const int tj = (t >> 5) * 8;
      float acc[4][8];
#pragma unroll
      for (int a = 0; a < 4; ++a)
#pragma unroll
        for (int b2 = 0; b2 < 8; ++b2) acc[a][b2] = 0.f;
#pragma unroll 4
      for (int r = 0; r < 1024; ++r) {
        const float* rowp = fr + r * CIN;
        float4 a4 = *(const float4*)(rowp + ti);
        float4 b4 = *(const float4*)(rowp + tj);
        float4 b5 = *(const float4*)(rowp + tj + 4);
        float av[4] = {a4.x, a4.y, a4.z, a4.w};
        float bv[8] = {b4.x, b4.y, b4.z, b4.w, b5.x, b5.y, b5.z, b5.w};
#pragma unroll
        for (int a = 0; a < 4; ++a)
#pragma unroll
          for (int b2 = 0; b2 < 8; ++b2) acc[a][b2] += av[a] * bv[b2];
      }
      float* G = wsf + WS_G;
#pragma unroll
      for (int a = 0; a < 4; ++a)
#pragma unroll
        for (int b2 = 0; b2 < 8; ++b2)
          atomicAdd(&G[(ti + a) * CIN + (tj + b2)], acc[a][b2]);
    } else {
      // ---------------- column sums of feat ----------------
      const int fb = g - 128;             // 0..7
      const size_t base = (size_t)fb * 16384;
      const int c = t & 127, rg = t >> 7; // 0..3
      float s = 0.f;
      for (int r = rg; r < 16384; r += 4)
        s += feat[(base + r) * CIN + c];
      s_fs[rg][c] = s;
      __syncthreads();
      if (t < 128) {
        float v = s_fs[0][t] + s_fs[1][t] + s_fs[2][t] + s_fs[3][t];
        atomicAdd(&wsf[WS_FSUM + t], v);
      }
    }
  }
}

// mean[c] = (fsum . W[c]) / M ; E[x^2][c] = W[c]^T G W[c] / M
__global__ __launch_bounds__(128) void finalize_k(
    const float* __restrict__ W, const float* __restrict__ gamma,
    const float* __restrict__ beta, float* __restrict__ wsf)
{
  const int c = blockIdx.x, i = threadIdx.x;
  const float* G = wsf + WS_G;
  const float* fsum = wsf + WS_FSUM;
  const float* Gi = G + i * CIN;
  const float* Wc = W + c * CIN;
  float td = 0.f;
#pragma unroll 8
  for (int j = 0; j < CIN; j += 4) {
    float4 g4 = *(const float4*)(Gi + j);
    float4 w4 = *(const float4*)(Wc + j);
    td += g4.x * w4.x + g4.y * w4.y + g4.z * w4.z + g4.w * w4.w;
  }
  const float wci = Wc[i];
  float q = wci * td;
  float m = fsum[i] * wci;
#pragma unroll
  for (int o = 32; o > 0; o >>= 1) {
    q += __shfl_xor(q, o, 64);
    m += __shfl_xor(m, o, 64);
  }
  __shared__ float sq[2], sm[2];
  if ((i & 63) == 0) { sq[i >> 6] = q; sm[i >> 6] = m; }
  __syncthreads();
  if (i == 0) {
    const float inv_m = 1.f / 131072.f;
    float mean = (sm[0] + sm[1]) * inv_m;
    float e2 = (sq[0] + sq[1]) * inv_m;
    float var = e2 - mean * mean;
    float rstd = rsqrtf(var + 1e-5f);
    float gs = gamma[c] * rstd;
    wsf[WS_GSCALE + c] = gs;
    wsf[WS_GBIAS + c] = beta[c] - mean * gs;
  }
}

// recompute x rows only at sampled indices, normalize + relu, gather coords
__global__ __launch_bounds__(256) void gather_k(
    const float* __restrict__ coord, const float* __restrict__ feat,
    const float* __restrict__ W, const float* __restrict__ wsf,
    const int* __restrict__ wsi, float* __restrict__ out)
{
  const int p = blockIdx.x, t = threadIdx.x;
  const int b = p >> 11;
  const int idx = wsi[p];
  const size_t row = (size_t)b * NPT + idx;
  __shared__ float lf[CIN];
  if (t < CIN) lf[t] = feat[row * CIN + t];
  __syncthreads();
  const float* Wc = W + t * CIN;
  float acc = 0.f;
#pragma unroll 8
  for (int k = 0; k < CIN; k += 4) {
    float4 w4 = *(const float4*)(Wc + k);
    acc += lf[k] * w4.x + lf[k + 1] * w4.y + lf[k + 2] * w4.z + lf[k + 3] * w4.w;
  }
  float y = fmaxf(fmaf(acc, wsf[WS_GSCALE + t], wsf[WS_GBIAS + t]), 0.f);
  out[OUT_FEAT + (size_t)p * COUT + t] = y;
  if (t < 3) out[OUT_COORD + p * 3 + t] = coord[row * 3 + t];
  if (p == 0 && t < 4) out[OUT_OFFS + t] = (float)((t + 1) * NS);
}

extern "C" void kernel_launch(void* const* d_in, const int* in_sizes, int n_in,
                              void* d_out, int out_size, void* d_ws, size_t ws_size,
                              hipStream_t stream)
{
  const float* coord = (const float*)d_in[0];
  const float* feat  = (const float*)d_in[1];
  // d_in[2] = offset (implied by constants)
  const float* W     = (const float*)d_in[3];
  const float* gamma = (const float*)d_in[4];
  const float* beta  = (const float*)d_in[5];
  float* wsf = (float*)d_ws;
  int* wsi = (int*)(wsf + WS_IDX);
  unsigned long long* slots = (unsigned long long*)(wsf + WS_SLOT);
  float* out = (float*)d_out;

  // zero Gram + colsum accumulators AND all sync slots (kills stale tags
  // across graph replays; stream-ordered before fused1)
  hipMemsetAsync(d_ws, 0, (WS_SLOT + 256) * sizeof(float), stream);

  fused1<<<152, THR, 0, stream>>>(coord, feat, wsf, wsi, slots);
  finalize_k<<<COUT, 128, 0, stream>>>(W, gamma, beta, wsf);
  gather_k<<<NB * NS, 256, 0, stream>>>(coord, feat, W, wsf, wsi, out);
}

// Round 16
// 4425.146 us; speedup vs baseline: 1.5864x; 1.2582x over previous
//
#include <hip/hip_runtime.h>

#define NB 4
#define NPT 32768
#define QPT 8192          // points per quarter-cloud
#define CIN 128
#define COUT 256
#define NS 2048
#define THR 512
#define PPT 16            // points per thread (QPT / PPT)

// ws float-offset layout
#define WS_G 0            // 128*128 Gram
#define WS_FSUM 16384     // 128 column sums
#define WS_SLOT 16512     // 4 clouds x 32 u64 (256B padded) = 256 floats
#define WS_GSCALE 16768   // 256
#define WS_GBIAS 17024    // 256
#define WS_IDX 17280      // 8192 ints

// d_out float-offset layout
#define OUT_COORD 0
#define OUT_FEAT 24576
#define OUT_OFFS 2121728

// FINAL (= round-12 kernel, the measured optimum of 15 structural variants).
// Complete exchange-structure ranking (unprofiled totals, us):
//   r12 4416 < r8 4746 < r13 5025 < r9 5091 < r15 5567 < r11 6060
//   < r14 7020 < r10 7646 < r5 8026
// Established facts:
//  * FPS = 2047 strictly serial iterations; coords/cloud = 384 KB >>
//    160 KB LDS/CU -> >=2 blocks/cloud forced -> one cross-block exchange
//    per iteration is irreducible.
//  * agent-scope atomics are serviced memory-side (~800 cyc/way, bypass
//    L1+L2); r13 falsified the same-XCD L2 fast path (%8 co-location not
//    schedulable). Exchange ~= 2 memory-side RTs ~= 1.3 us/iter.
//  * Fewer pollers win (r12's 4-lane poll, +7% vs r8); poll/store flooding
//    and barrier-free many-slot designs lose (r10/r14); detection funneled
//    through one wave loses (r15: min-over-8-pollers beats single+mailbox).
//  * Compute is NOT the bottleneck: VALUBusy ~3.5%, HBM ~0.4% at r12 --
//    the kernel is cross-XCD-sync-latency bound. ~2.1 us/iter ~= 4.3 ms
//    structural floor; measured 4.42 ms.
//  * Coords LDS-resident (compiler never register-allocates them; VGPR
//    counts 48-88 across all attempts regardless of knobs). dv[16] in regs.
//  * WRITE ~66 MB = Gram's 2.1M memory-side atomics (expected, harmless).
//    rocprof inflates spin kernels -> compare unprofiled totals only.
//  * Tagged monotone key it<<48 | dbits<<15 | (32767-gidx): bigger dist
//    wins, tie -> lower index (np.argmax first-occurrence); stale slot
//    values lose atomicMax automatically; slot reuse at parity distance 2
//    is safe (store(it+2) happens-after passing poll(it+1), which requires
//    all blocks' store(it+1), post-B0(it+1), after all waves consumed it).
__global__ __launch_bounds__(THR) void fused1(
    const float* __restrict__ coord, const float* __restrict__ feat,
    float* __restrict__ wsf, int* __restrict__ wsi,
    unsigned long long* __restrict__ slots)
{
  __shared__ float2 lxy[QPT];                 // 65536 B
  __shared__ float lz[QPT];                   // 32768 B
  __shared__ unsigned long long s_key[2];
  __shared__ float s_fs[4][128];              // colsum scratch (2 KB)

  const int bid = blockIdx.x;
  const int t = threadIdx.x;
  const bool is_fps = (bid < 32) && ((bid & 7) < 4);

  if (is_fps) {
    // ---------------- FPS: cloud cl, quarter h ----------------
    const int cl = bid & 3;
    const int h = bid >> 3;            // 0..3
    const int gbase = h * QPT;
    const float* xyz = coord + (size_t)cl * NPT * 3;
    int* idx_out = wsi + cl * NS;
    unsigned long long* slot = slots + cl * 32;   // 256B-padded per cloud

    float dv[PPT];
#pragma unroll
    for (int j = 0; j < PPT; ++j) {
      const int l = j * THR + t;
      const int p = gbase + l;
      lxy[l] = make_float2(xyz[p * 3 + 0], xyz[p * 3 + 1]);
      lz[l] = xyz[p * 3 + 2];
      dv[j] = 1e10f;
    }
    if (t == 0) {
      if (h == 0) idx_out[0] = 0;      // every cloud writes sample 0
      s_key[0] = s_key[1] = 0ull;      // tag 0 < any it>=1
    }
    float cx = xyz[0], cy = xyz[1], cz = xyz[2];   // same-address broadcast
    __syncthreads();                   // LDS coords + s_key ready

    const int lane = t & 63;
    for (int it = 1; it < NS; ++it) {
      const int par = it & 1;
      const unsigned long long utag = (unsigned long long)it;
      float bd = -1.f;
      int bj = 0;
      // exact numpy-f32 distance: plain muls (asm blocks fma contraction),
      // (sx+sy)+sz, v_min_f32 update; argmax tracked inline (strict > keeps
      // lowest j = lowest global index within this thread's stride).
#pragma unroll
      for (int j = 0; j < PPT; ++j) {
        const int l = j * THR + t;
        const float2 xy = lxy[l];
        const float zz = lz[l];
        float dx = xy.x - cx, dy = xy.y - cy, dz = zz - cz;
        float sx = dx * dx, sy = dy * dy, sz = dz * dz;
        asm volatile("" : "+v"(sx), "+v"(sy), "+v"(sz));
        float nd = fminf(dv[j], (sx + sy) + sz);
        dv[j] = nd;
        if (nd > bd) { bd = nd; bj = j; }
      }
      const int gidx = gbase + bj * THR + t;
      // tagged monotone key: bigger dist wins, tie -> lower idx (np.argmax)
      const unsigned long long tkey =
          (utag << 48) |
          ((unsigned long long)(unsigned)__float_as_int(bd) << 15) |
          (unsigned)(32767 - gidx);
      unsigned long long wkey = tkey;
#pragma unroll
      for (int o = 32; o > 0; o >>= 1) {
        unsigned long long ok = __shfl_xor(wkey, o, 64);
        wkey = ok > wkey ? ok : wkey;
      }
      if (lane == 0) atomicMax(&s_key[par], wkey);
      __syncthreads();                 // the ONLY barrier per iter
      const unsigned long long skey = s_key[par];
      if (tkey == skey)                // unique winner thread (gidx unique)
        __hip_atomic_store(&slot[par * 4 + h], skey,
                           __ATOMIC_RELAXED, __HIP_MEMORY_SCOPE_AGENT);
      // poll: lanes 0-3 only -> ONE 32B request per wave per round
      unsigned long long v = 0;
      for (;;) {
        if (lane < 4)
          v = __hip_atomic_load(&slot[par * 4 + lane],
                                __ATOMIC_RELAXED, __HIP_MEMORY_SCOPE_AGENT);
        const bool ok = (lane >= 4) || ((v >> 48) == utag);
        if (__all((int)ok)) break;
        __builtin_amdgcn_s_sleep(1);   // thin the retry traffic
      }
      unsigned long long o1 = __shfl_xor(v, 1, 64);
      v = o1 > v ? o1 : v;
      unsigned long long o2 = __shfl_xor(v, 2, 64);
      v = o2 > v ? o2 : v;
      v = __shfl(v, 0, 64);            // broadcast merged winner to all lanes
      const int widx = 32767 - (int)(v & 0x7fff);
      if (h == 0 && t == 0) idx_out[it] = widx;
      cx = xyz[widx * 3 + 0];          // same-address broadcast load (L2)
      cy = xyz[widx * 3 + 1];
      cz = xyz[widx * 3 + 2];
    }
  } else {
    // non-FPS linear index: 16 fillers inside bid<32, rest from 32 up
    const int g = (bid < 32) ? ((bid >> 3) * 4 + (bid & 7) - 4) : (bid - 16);
    if (g < 128) {
      // ---------------- Gram partial: G += chunk^T chunk ----------------
      const float* fr = feat + (size_t)g * 1024 * CIN;
      const int ti = (t & 31) * 4;
      const int tj = (t >> 5) * 8;
      float acc[4][8];
#pragma unroll
      for (int a = 0; a < 4; ++a)
#pragma unroll
        for (int b2 = 0; b2 < 8; ++b2) acc[a][b2] = 0.f;
#pragma unroll 4
      for (int r = 0; r < 1024; ++r) {
        const float* rowp = fr + r * CIN;
        float4 a4 = *(const float4*)(rowp + ti);
        float4 b4 = *(const float4*)(rowp + tj);
        float4 b5 = *(const float4*)(rowp + tj + 4);
        float av[4] = {a4.x, a4.y, a4.z, a4.w};
        float bv[8] = {b4.x, b4.y, b4.z, b4.w, b5.x, b5.y, b5.z, b5.w};
#pragma unroll
        for (int a = 0; a < 4; ++a)
#pragma unroll
          for (int b2 = 0; b2 < 8; ++b2) acc[a][b2] += av[a] * bv[b2];
      }
      float* G = wsf + WS_G;
#pragma unroll
      for (int a = 0; a < 4; ++a)
#pragma unroll
        for (int b2 = 0; b2 < 8; ++b2)
          atomicAdd(&G[(ti + a) * CIN + (tj + b2)], acc[a][b2]);
    } else {
      // ---------------- column sums of feat ----------------
      const int fb = g - 128;             // 0..7
      const size_t base = (size_t)fb * 16384;
      const int c = t & 127, rg = t >> 7; // 0..3
      float s = 0.f;
      for (int r = rg; r < 16384; r += 4)
        s += feat[(base + r) * CIN + c];
      s_fs[rg][c] = s;
      __syncthreads();
      if (t < 128) {
        float v = s_fs[0][t] + s_fs[1][t] + s_fs[2][t] + s_fs[3][t];
        atomicAdd(&wsf[WS_FSUM + t], v);
      }
    }
  }
}

// mean[c] = (fsum . W[c]) / M ; E[x^2][c] = W[c]^T G W[c] / M
__global__ __launch_bounds__(128) void finalize_k(
    const float* __restrict__ W, const float* __restrict__ gamma,
    const float* __restrict__ beta, float* __restrict__ wsf)
{
  const int c = blockIdx.x, i = threadIdx.x;
  const float* G = wsf + WS_G;
  const float* fsum = wsf + WS_FSUM;
  const float* Gi = G + i * CIN;
  const float* Wc = W + c * CIN;
  float td = 0.f;
#pragma unroll 8
  for (int j = 0; j < CIN; j += 4) {
    float4 g4 = *(const float4*)(Gi + j);
    float4 w4 = *(const float4*)(Wc + j);
    td += g4.x * w4.x + g4.y * w4.y + g4.z * w4.z + g4.w * w4.w;
  }
  const float wci = Wc[i];
  float q = wci * td;
  float m = fsum[i] * wci;
#pragma unroll
  for (int o = 32; o > 0; o >>= 1) {
    q += __shfl_xor(q, o, 64);
    m += __shfl_xor(m, o, 64);
  }
  __shared__ float sq[2], sm[2];
  if ((i & 63) == 0) { sq[i >> 6] = q; sm[i >> 6] = m; }
  __syncthreads();
  if (i == 0) {
    const float inv_m = 1.f / 131072.f;
    float mean = (sm[0] + sm[1]) * inv_m;
    float e2 = (sq[0] + sq[1]) * inv_m;
    float var = e2 - mean * mean;
    float rstd = rsqrtf(var + 1e-5f);
    float gs = gamma[c] * rstd;
    wsf[WS_GSCALE + c] = gs;
    wsf[WS_GBIAS + c] = beta[c] - mean * gs;
  }
}

// recompute x rows only at sampled indices, normalize + relu, gather coords
__global__ __launch_bounds__(256) void gather_k(
    const float* __restrict__ coord, const float* __restrict__ feat,
    const float* __restrict__ W, const float* __restrict__ wsf,
    const int* __restrict__ wsi, float* __restrict__ out)
{
  const int p = blockIdx.x, t = threadIdx.x;
  const int b = p >> 11;
  const int idx = wsi[p];
  const size_t row = (size_t)b * NPT + idx;
  __shared__ float lf[CIN];
  if (t < CIN) lf[t] = feat[row * CIN + t];
  __syncthreads();
  const float* Wc = W + t * CIN;
  float acc = 0.f;
#pragma unroll 8
  for (int k = 0; k < CIN; k += 4) {
    float4 w4 = *(const float4*)(Wc + k);
    acc += lf[k] * w4.x + lf[k + 1] * w4.y + lf[k + 2] * w4.z + lf[k + 3] * w4.w;
  }
  float y = fmaxf(fmaf(acc, wsf[WS_GSCALE + t], wsf[WS_GBIAS + t]), 0.f);
  out[OUT_FEAT + (size_t)p * COUT + t] = y;
  if (t < 3) out[OUT_COORD + p * 3 + t] = coord[row * 3 + t];
  if (p == 0 && t < 4) out[OUT_OFFS + t] = (float)((t + 1) * NS);
}

extern "C" void kernel_launch(void* const* d_in, const int* in_sizes, int n_in,
                              void* d_out, int out_size, void* d_ws, size_t ws_size,
                              hipStream_t stream)
{
  const float* coord = (const float*)d_in[0];
  const float* feat  = (const float*)d_in[1];
  // d_in[2] = offset (implied by constants)
  const float* W     = (const float*)d_in[3];
  const float* gamma = (const float*)d_in[4];
  const float* beta  = (const float*)d_in[5];
  float* wsf = (float*)d_ws;
  int* wsi = (int*)(wsf + WS_IDX);
  unsigned long long* slots = (unsigned long long*)(wsf + WS_SLOT);
  float* out = (float*)d_out;

  // zero Gram + colsum accumulators AND all sync slots (kills stale tags
  // across graph replays; stream-ordered before fused1)
  hipMemsetAsync(d_ws, 0, (WS_SLOT + 256) * sizeof(float), stream);

  fused1<<<152, THR, 0, stream>>>(coord, feat, wsf, wsi, slots);
  finalize_k<<<COUT, 128, 0, stream>>>(W, gamma, beta, wsf);
  gather_k<<<NB * NS, 256, 0, stream>>>(coord, feat, W, wsf, wsi, out);
}